// Round 3
// baseline (202.094 us; speedup 1.0000x reference)
//
#include <hip/hip_runtime.h>
#include <hip/hip_bf16.h>

typedef unsigned short ushort;
typedef __attribute__((ext_vector_type(8))) short bf16x8;     // MFMA A/B frag (8 bf16)
typedef __attribute__((ext_vector_type(8))) unsigned short ushort8;
typedef __attribute__((ext_vector_type(4))) float f32x4;      // MFMA C/D frag

__device__ __forceinline__ ushort f2bf(float f) {
    union { float f; unsigned u; } v; v.f = f;
    unsigned r = v.u + 0x7FFFu + ((v.u >> 16) & 1u);
    return (ushort)(r >> 16);
}
__device__ __forceinline__ float bf2f(ushort u) {
    union { unsigned u; float f; } v; v.u = ((unsigned)u) << 16;
    return v.f;
}

// ---------------------------------------------------------------------------
// Transpose + fp32->bf16 convert:  dst[n*K + k] = bf16(src[k*N + n])
// ---------------------------------------------------------------------------
__global__ void transpose_w(const float* __restrict__ src, ushort* __restrict__ dst,
                            int K, int N) {
    int i = blockIdx.x * 256 + threadIdx.x;
    if (i >= K * N) return;
    int k = i / N, n = i % N;
    dst[(size_t)n * K + k] = f2bf(src[i]);
}

// ---------------------------------------------------------------------------
// q-projection: C_bf16[m, 0:320] = A_f32[m, 0:320] @ Bt^T   (Bt is [n][k])
// grid.x = M/64, block = 256 (4 waves). Wave w owns cols [80w, 80w+80).
// ---------------------------------------------------------------------------
__global__ __launch_bounds__(256) void gemm_qproj(
    const float* __restrict__ A, const ushort* __restrict__ Bt,
    ushort* __restrict__ C)
{
    __shared__ ushort A_lds[64 * 40];   // 64 rows x 32k, stride 40 (2-way conflict max)
    __shared__ ushort B_lds[320 * 40];  // 320 cols x 32k
    const int tid = threadIdx.x;
    const int w = tid >> 6, l = tid & 63;
    const int c15 = l & 15, khi = (l >> 4) * 8;
    const int m0 = blockIdx.x * 64;
    f32x4 acc[4][5] = {};
    for (int kk = 0; kk < 320; kk += 32) {
        {   // stage A (convert fp32->bf16)
            int r = tid >> 2, p = (tid & 3) * 8;
            const float* s = A + (size_t)(m0 + r) * 320 + kk + p;
            ushort* d = &A_lds[r * 40 + p];
            #pragma unroll
            for (int j = 0; j < 8; ++j) d[j] = f2bf(s[j]);
        }
        #pragma unroll
        for (int i = 0; i < 5; ++i) {   // stage B (already bf16, pre-transposed)
            int idx = tid + i * 256;
            int n = idx >> 2, p = (idx & 3) * 8;
            *(ushort8*)&B_lds[n * 40 + p] = *(const ushort8*)(Bt + (size_t)n * 320 + kk + p);
        }
        __syncthreads();
        bf16x8 a[4];
        #pragma unroll
        for (int mf = 0; mf < 4; ++mf)
            a[mf] = *(const bf16x8*)&A_lds[(mf * 16 + c15) * 40 + khi];
        #pragma unroll
        for (int f = 0; f < 5; ++f) {
            bf16x8 b = *(const bf16x8*)&B_lds[(w * 80 + f * 16 + c15) * 40 + khi];
            #pragma unroll
            for (int mf = 0; mf < 4; ++mf)
                acc[mf][f] = __builtin_amdgcn_mfma_f32_16x16x32_bf16(a[mf], b, acc[mf][f], 0, 0, 0);
        }
        __syncthreads();
    }
    const int rbase = (l >> 4) * 4;
    #pragma unroll
    for (int mf = 0; mf < 4; ++mf)
        #pragma unroll
        for (int f = 0; f < 5; ++f) {
            int col = w * 80 + f * 16 + c15;
            #pragma unroll
            for (int r = 0; r < 4; ++r)
                C[(size_t)(m0 + mf * 16 + rbase + r) * 320 + col] = f2bf(acc[mf][f][r]);
        }
}

// ---------------------------------------------------------------------------
// out-projection: out_f32[m, n] = A_bf16[m, 0:320] @ Wo_t^T + bo[n]
// ---------------------------------------------------------------------------
__global__ __launch_bounds__(256) void gemm_out(
    const ushort* __restrict__ A, const ushort* __restrict__ Bt,
    const float* __restrict__ bias, float* __restrict__ C)
{
    __shared__ ushort A_lds[64 * 40];
    __shared__ ushort B_lds[320 * 40];
    const int tid = threadIdx.x;
    const int w = tid >> 6, l = tid & 63;
    const int c15 = l & 15, khi = (l >> 4) * 8;
    const int m0 = blockIdx.x * 64;
    f32x4 acc[4][5] = {};
    for (int kk = 0; kk < 320; kk += 32) {
        {
            int r = tid >> 2, p = (tid & 3) * 8;
            *(ushort8*)&A_lds[r * 40 + p] = *(const ushort8*)(A + (size_t)(m0 + r) * 320 + kk + p);
        }
        #pragma unroll
        for (int i = 0; i < 5; ++i) {
            int idx = tid + i * 256;
            int n = idx >> 2, p = (idx & 3) * 8;
            *(ushort8*)&B_lds[n * 40 + p] = *(const ushort8*)(Bt + (size_t)n * 320 + kk + p);
        }
        __syncthreads();
        bf16x8 a[4];
        #pragma unroll
        for (int mf = 0; mf < 4; ++mf)
            a[mf] = *(const bf16x8*)&A_lds[(mf * 16 + c15) * 40 + khi];
        #pragma unroll
        for (int f = 0; f < 5; ++f) {
            bf16x8 b = *(const bf16x8*)&B_lds[(w * 80 + f * 16 + c15) * 40 + khi];
            #pragma unroll
            for (int mf = 0; mf < 4; ++mf)
                acc[mf][f] = __builtin_amdgcn_mfma_f32_16x16x32_bf16(a[mf], b, acc[mf][f], 0, 0, 0);
        }
        __syncthreads();
    }
    const int rbase = (l >> 4) * 4;
    #pragma unroll
    for (int mf = 0; mf < 4; ++mf)
        #pragma unroll
        for (int f = 0; f < 5; ++f) {
            int col = w * 80 + f * 16 + c15;
            #pragma unroll
            for (int r = 0; r < 4; ++r)
                C[(size_t)(m0 + mf * 16 + rbase + r) * 320 + col] = acc[mf][f][r] + bias[col];
        }
}

// ---------------------------------------------------------------------------
// k/v projection: M=616 rows (8*77), K=768. 8 waves: w<4 -> K output, w>=4 -> V.
// ---------------------------------------------------------------------------
__global__ __launch_bounds__(512) void gemm_kv(
    const float* __restrict__ E, const ushort* __restrict__ Wk_t,
    const ushort* __restrict__ Wv_t, ushort* __restrict__ Kb, ushort* __restrict__ Vb)
{
    __shared__ ushort A_lds[64 * 40];
    __shared__ ushort B_lds[2 * 320 * 40];
    const int tid = threadIdx.x;
    const int w = tid >> 6, l = tid & 63;
    const int c15 = l & 15, khi = (l >> 4) * 8;
    const int mat = w >> 2, wl = w & 3;
    const int m0 = blockIdx.x * 64;
    f32x4 acc[4][5] = {};
    for (int kk = 0; kk < 768; kk += 32) {
        {   // stage A rows (convert, guard M=616)
            int r = tid >> 3, p = (tid & 7) * 4;
            int m = m0 + r;
            ushort* d = &A_lds[r * 40 + p];
            if (m < 616) {
                const float* s = E + (size_t)m * 768 + kk + p;
                #pragma unroll
                for (int j = 0; j < 4; ++j) d[j] = f2bf(s[j]);
            } else {
                #pragma unroll
                for (int j = 0; j < 4; ++j) d[j] = 0;
            }
        }
        #pragma unroll
        for (int i = 0; i < 5; ++i) {   // stage both B matrices
            int idx = tid + i * 512;
            int mt = idx >= 1280; int ii = idx - mt * 1280;
            int n = ii >> 2, p = (ii & 3) * 8;
            const ushort* src = (mt ? Wv_t : Wk_t) + (size_t)n * 768 + kk + p;
            *(ushort8*)&B_lds[(mt * 320 + n) * 40 + p] = *(const ushort8*)src;
        }
        __syncthreads();
        bf16x8 a[4];
        #pragma unroll
        for (int mf = 0; mf < 4; ++mf)
            a[mf] = *(const bf16x8*)&A_lds[(mf * 16 + c15) * 40 + khi];
        #pragma unroll
        for (int f = 0; f < 5; ++f) {
            bf16x8 b = *(const bf16x8*)&B_lds[(mat * 320 + wl * 80 + f * 16 + c15) * 40 + khi];
            #pragma unroll
            for (int mf = 0; mf < 4; ++mf)
                acc[mf][f] = __builtin_amdgcn_mfma_f32_16x16x32_bf16(a[mf], b, acc[mf][f], 0, 0, 0);
        }
        __syncthreads();
    }
    ushort* dst = mat ? Vb : Kb;
    const int rbase = (l >> 4) * 4;
    #pragma unroll
    for (int mf = 0; mf < 4; ++mf)
        #pragma unroll
        for (int f = 0; f < 5; ++f) {
            int col = wl * 80 + f * 16 + c15;
            #pragma unroll
            for (int r = 0; r < 4; ++r) {
                int row = m0 + mf * 16 + rbase + r;
                if (row < 616) dst[(size_t)row * 320 + col] = f2bf(acc[mf][f][r]);
            }
        }
}

// ---------------------------------------------------------------------------
// v'[p][m][c] = sum_e mapper[p][m][e] * v[5+p][e][c]   (tiny; 231 blocks x 320 thr)
// ---------------------------------------------------------------------------
__global__ void vprime_k(const float* __restrict__ mapper, const ushort* __restrict__ Vb,
                         ushort* __restrict__ VP)
{
    int pm = blockIdx.x;            // p*77 + m
    int p = pm / 77;
    __shared__ float mp[77];
    int tid = threadIdx.x;          // 320 threads
    if (tid < 77) mp[tid] = mapper[(size_t)pm * 77 + tid];
    __syncthreads();
    float acc = 0.f;
    const ushort* vcol = Vb + (size_t)(5 + p) * 77 * 320 + tid;
    for (int e = 0; e < 77; ++e) acc += mp[e] * bf2f(vcol[(size_t)e * 320]);
    VP[(size_t)pm * 320 + tid] = f2bf(acc);
}

// ---------------------------------------------------------------------------
// Fused attention. grid = (T/64, H=8, 5). Block 256 (4 waves), wave w owns rows
// [16w,16w+16) of the 64-row Q tile. b==4 block also produces batches 5..7 via v'.
// ---------------------------------------------------------------------------
#define ATT_SCALE 0.15811388300841897f   // 1/sqrt(40)
__global__ __launch_bounds__(256) void attn_k(
    const ushort* __restrict__ Q, const ushort* __restrict__ K,
    const ushort* __restrict__ V, const ushort* __restrict__ VP,
    ushort* __restrict__ O)
{
    __shared__ ushort Q_lds[64 * 72];        // [row][k0..63], d padded 40->64
    __shared__ ushort K_lds[80 * 72];        // [s][k0..63], s padded 77->80
    __shared__ ushort P_lds[64 * 104];       // [row][s0..95], stride 104
    __shared__ ushort V_lds[4 * 48 * 104];   // [tgt][dcol0..47][s0..95]
    const int tid = threadIdx.x;
    const int w = tid >> 6, l = tid & 63;
    const int c15 = l & 15, khi = (l >> 4) * 8;
    const int b = blockIdx.z, h = blockIdx.y, t0 = blockIdx.x * 64;
    const int ntgt = (b == 4) ? 4 : 1;

    for (int i = tid; i < 64 * 64; i += 256) {      // Q tile
        int r = i >> 6, kd = i & 63;
        Q_lds[r * 72 + kd] = (kd < 40) ? Q[(size_t)(b * 4096 + t0 + r) * 320 + h * 40 + kd] : 0;
    }
    for (int i = tid; i < 80 * 64; i += 256) {      // K tile
        int s = i >> 6, kd = i & 63;
        K_lds[s * 72 + kd] = (s < 77 && kd < 40) ? K[(size_t)(b * 77 + s) * 320 + h * 40 + kd] : 0;
    }
    for (int i = tid; i < ntgt * 48 * 96; i += 256) {   // V tiles (transposed: [dcol][s])
        int tgt = i / (48 * 96); int rem = i - tgt * (48 * 96);
        int dc = rem / 96, s = rem - dc * 96;
        ushort val = 0;
        if (s < 77 && dc < 40)
            val = (tgt == 0) ? V[(size_t)(b * 77 + s) * 320 + h * 40 + dc]
                             : VP[(size_t)((tgt - 1) * 77 + s) * 320 + h * 40 + dc];
        V_lds[(tgt * 48 + dc) * 104 + s] = val;
    }
    for (int i = tid; i < 64 * 24; i += 256) {      // zero P pad cols 80..103
        int r = i / 24, cc = 80 + (i - r * 24);
        P_lds[r * 104 + cc] = 0;
    }
    __syncthreads();

    // QK^T : rows 16w..16w+15, cols 0..79 (5 frags), K-dim 64 (2 steps)
    f32x4 sacc[5] = {};
    bf16x8 qa[2];
    #pragma unroll
    for (int kt = 0; kt < 2; ++kt)
        qa[kt] = *(const bf16x8*)&Q_lds[(w * 16 + c15) * 72 + kt * 32 + khi];
    #pragma unroll
    for (int f = 0; f < 5; ++f)
        #pragma unroll
        for (int kt = 0; kt < 2; ++kt) {
            bf16x8 kb = *(const bf16x8*)&K_lds[(f * 16 + c15) * 72 + kt * 32 + khi];
            sacc[f] = __builtin_amdgcn_mfma_f32_16x16x32_bf16(qa[kt], kb, sacc[f], 0, 0, 0);
        }

    // masked softmax over s (per C-row; 16-lane shuffle reduce)
    float pv[5][4];
    #pragma unroll
    for (int r = 0; r < 4; ++r) {
        float mx = -1e30f;
        #pragma unroll
        for (int f = 0; f < 5; ++f) {
            float vs = sacc[f][r] * ATT_SCALE;
            bool valid = (f < 4) || (c15 < 13);     // col = 16f + c15 < 77
            pv[f][r] = valid ? vs : -1e30f;
            mx = fmaxf(mx, pv[f][r]);
        }
        #pragma unroll
        for (int d = 1; d < 16; d <<= 1) mx = fmaxf(mx, __shfl_xor(mx, d));
        float sum = 0.f;
        #pragma unroll
        for (int f = 0; f < 5; ++f) {
            float e = (pv[f][r] > -1e29f) ? __expf(pv[f][r] - mx) : 0.f;
            pv[f][r] = e; sum += e;
        }
        #pragma unroll
        for (int d = 1; d < 16; d <<= 1) sum += __shfl_xor(sum, d);
        float inv = 1.f / sum;
        #pragma unroll
        for (int f = 0; f < 5; ++f) pv[f][r] *= inv;
    }
    const int rbase = (l >> 4) * 4;
    #pragma unroll
    for (int r = 0; r < 4; ++r)
        #pragma unroll
        for (int f = 0; f < 5; ++f)
            P_lds[(w * 16 + rbase + r) * 104 + f * 16 + c15] = f2bf(pv[f][r]);
    __syncthreads();

    // PV: out rows 16w.., dcols 0..47 (3 frags), K-dim 96 (3 steps)
    bf16x8 pa[3];
    #pragma unroll
    for (int kt = 0; kt < 3; ++kt)
        pa[kt] = *(const bf16x8*)&P_lds[(w * 16 + c15) * 104 + kt * 32 + khi];
    for (int tgt = 0; tgt < ntgt; ++tgt) {
        f32x4 oacc[3] = {};
        #pragma unroll
        for (int f = 0; f < 3; ++f)
            #pragma unroll
            for (int kt = 0; kt < 3; ++kt) {
                bf16x8 vb = *(const bf16x8*)&V_lds[(tgt * 48 + f * 16 + c15) * 104 + kt * 32 + khi];
                oacc[f] = __builtin_amdgcn_mfma_f32_16x16x32_bf16(pa[kt], vb, oacc[f], 0, 0, 0);
            }
        int bt = b + tgt;
        #pragma unroll
        for (int f = 0; f < 3; ++f) {
            int col = f * 16 + c15;
            if (col < 40) {
                #pragma unroll
                for (int r = 0; r < 4; ++r)
                    O[(size_t)(bt * 4096 + t0 + w * 16 + rbase + r) * 320 + h * 40 + col]
                        = f2bf(oacc[f][r]);
            }
        }
    }
}

// ---------------------------------------------------------------------------
extern "C" void kernel_launch(void* const* d_in, const int* in_sizes, int n_in,
                              void* d_out, int out_size, void* d_ws, size_t ws_size,
                              hipStream_t stream) {
    (void)in_sizes; (void)n_in; (void)out_size; (void)ws_size;
    const float* hs     = (const float*)d_in[0];   // (8,4096,320)
    const float* ehs    = (const float*)d_in[1];   // (8,77,768)
    const float* mapper = (const float*)d_in[2];   // (3,77,77)
    const float* Wq     = (const float*)d_in[3];   // (320,320)
    const float* Wk     = (const float*)d_in[4];   // (768,320)
    const float* Wv     = (const float*)d_in[5];   // (768,320)
    const float* Wo     = (const float*)d_in[6];   // (320,320)
    const float* bo     = (const float*)d_in[7];   // (320,)
    float* out = (float*)d_out;

    ushort* ws   = (ushort*)d_ws;                  // ~36.4 MB of bf16 scratch
    ushort* Wq_t = ws;                             // 320*320
    ushort* Wk_t = Wq_t + 320 * 320;               // 320*768
    ushort* Wv_t = Wk_t + 320 * 768;
    ushort* Wo_t = Wv_t + 320 * 768;               // 320*320
    ushort* Qb   = Wo_t + 320 * 320;               // 20480*320
    ushort* Kb   = Qb + 20480 * 320;               // 616*320
    ushort* Vb   = Kb + 616 * 320;
    ushort* VP   = Vb + 616 * 320;                 // 231*320
    ushort* AO   = VP + 231 * 320;                 // 32768*320

    transpose_w<<<400, 256, 0, stream>>>(Wq, Wq_t, 320, 320);
    transpose_w<<<960, 256, 0, stream>>>(Wk, Wk_t, 768, 320);
    transpose_w<<<960, 256, 0, stream>>>(Wv, Wv_t, 768, 320);
    transpose_w<<<400, 256, 0, stream>>>(Wo, Wo_t, 320, 320);
    gemm_kv<<<10, 512, 0, stream>>>(ehs, Wk_t, Wv_t, Kb, Vb);
    gemm_qproj<<<320, 256, 0, stream>>>(hs, Wq_t, Qb);
    vprime_k<<<231, 320, 0, stream>>>(mapper, Vb, VP);
    attn_k<<<dim3(64, 8, 5), 256, 0, stream>>>(Qb, Kb, Vb, VP, AO);
    gemm_out<<<512, 256, 0, stream>>>(AO, Wo_t, bo, out);
}

// Round 4
// 116.093 us; speedup vs baseline: 1.7408x; 1.7408x over previous
//
#include <hip/hip_runtime.h>
#include <hip/hip_bf16.h>

typedef unsigned short ushort;
typedef __attribute__((ext_vector_type(8))) short bf16x8;     // MFMA A/B frag (8 bf16)
typedef __attribute__((ext_vector_type(8))) unsigned short ushort8;
typedef __attribute__((ext_vector_type(4))) float f32x4;      // MFMA C/D frag
typedef __attribute__((ext_vector_type(4))) float float4v;

__device__ __forceinline__ ushort f2bf(float f) {
    union { float f; unsigned u; } v; v.f = f;
    unsigned r = v.u + 0x7FFFu + ((v.u >> 16) & 1u);
    return (ushort)(r >> 16);
}
__device__ __forceinline__ float bf2f(ushort u) {
    union { unsigned u; float f; } v; v.u = ((unsigned)u) << 16;
    return v.f;
}

// ---------------------------------------------------------------------------
// Merged LDS-tiled transpose + fp32->bf16 for all four weights.
// dst[n*K + k] = bf16(src[k*320 + n]);  N = 320 for all, K in {320,768}.
// Tiles 32x32; grid = 100 + 240 + 240 + 100 = 680 blocks of 256.
// ---------------------------------------------------------------------------
__global__ __launch_bounds__(256) void transpose_all(
    const float* __restrict__ Wq, const float* __restrict__ Wk,
    const float* __restrict__ Wv, const float* __restrict__ Wo,
    ushort* __restrict__ Wq_t, ushort* __restrict__ Wk_t,
    ushort* __restrict__ Wv_t, ushort* __restrict__ Wo_t)
{
    __shared__ ushort t[32][33];
    int b = blockIdx.x;
    const float* src; ushort* dst; int K; int tb;
    if (b < 100)      { src = Wq; dst = Wq_t; K = 320; tb = b; }
    else if (b < 340) { src = Wk; dst = Wk_t; K = 768; tb = b - 100; }
    else if (b < 580) { src = Wv; dst = Wv_t; K = 768; tb = b - 340; }
    else              { src = Wo; dst = Wo_t; K = 320; tb = b - 580; }
    int tc = tb % 10, tr = tb / 10;               // tile col (n), tile row (k)
    int tx = threadIdx.x & 31, ty = threadIdx.x >> 5;
    #pragma unroll
    for (int p = 0; p < 4; ++p) {
        int k = tr * 32 + ty + p * 8, n = tc * 32 + tx;
        t[ty + p * 8][tx] = f2bf(src[(size_t)k * 320 + n]);
    }
    __syncthreads();
    #pragma unroll
    for (int p = 0; p < 4; ++p) {
        int n = tc * 32 + ty + p * 8, k = tr * 32 + tx;
        dst[(size_t)n * K + k] = t[tx][ty + p * 8];
    }
}

// ---------------------------------------------------------------------------
// q-projection: C_bf16[m, 0:320] = A_f32[m, 0:320] @ Bt^T   (Bt is [n][k])
// ---------------------------------------------------------------------------
__global__ __launch_bounds__(256) void gemm_qproj(
    const float* __restrict__ A, const ushort* __restrict__ Bt,
    ushort* __restrict__ C)
{
    __shared__ ushort A_lds[64 * 40];
    __shared__ ushort B_lds[320 * 40];
    const int tid = threadIdx.x;
    const int w = tid >> 6, l = tid & 63;
    const int c15 = l & 15, khi = (l >> 4) * 8;
    const int m0 = blockIdx.x * 64;
    f32x4 acc[4][5] = {};
    for (int kk = 0; kk < 320; kk += 32) {
        {   // stage A (convert fp32->bf16), vectorized float4 x2
            int r = tid >> 2, p = (tid & 3) * 8;
            const float4v* s = (const float4v*)(A + (size_t)(m0 + r) * 320 + kk + p);
            float4v x0 = s[0], x1 = s[1];
            ushort* d = &A_lds[r * 40 + p];
            d[0]=f2bf(x0.x); d[1]=f2bf(x0.y); d[2]=f2bf(x0.z); d[3]=f2bf(x0.w);
            d[4]=f2bf(x1.x); d[5]=f2bf(x1.y); d[6]=f2bf(x1.z); d[7]=f2bf(x1.w);
        }
        #pragma unroll
        for (int i = 0; i < 5; ++i) {
            int idx = tid + i * 256;
            int n = idx >> 2, p = (idx & 3) * 8;
            *(ushort8*)&B_lds[n * 40 + p] = *(const ushort8*)(Bt + (size_t)n * 320 + kk + p);
        }
        __syncthreads();
        bf16x8 a[4];
        #pragma unroll
        for (int mf = 0; mf < 4; ++mf)
            a[mf] = *(const bf16x8*)&A_lds[(mf * 16 + c15) * 40 + khi];
        #pragma unroll
        for (int f = 0; f < 5; ++f) {
            bf16x8 b = *(const bf16x8*)&B_lds[(w * 80 + f * 16 + c15) * 40 + khi];
            #pragma unroll
            for (int mf = 0; mf < 4; ++mf)
                acc[mf][f] = __builtin_amdgcn_mfma_f32_16x16x32_bf16(a[mf], b, acc[mf][f], 0, 0, 0);
        }
        __syncthreads();
    }
    const int rbase = (l >> 4) * 4;
    #pragma unroll
    for (int mf = 0; mf < 4; ++mf)
        #pragma unroll
        for (int f = 0; f < 5; ++f) {
            int col = w * 80 + f * 16 + c15;
            #pragma unroll
            for (int r = 0; r < 4; ++r)
                C[(size_t)(m0 + mf * 16 + rbase + r) * 320 + col] = f2bf(acc[mf][f][r]);
        }
}

// ---------------------------------------------------------------------------
// out-projection: out_f32[m, n] = A_bf16[m, 0:320] @ Wo_t^T + bo[n]
// ---------------------------------------------------------------------------
__global__ __launch_bounds__(256) void gemm_out(
    const ushort* __restrict__ A, const ushort* __restrict__ Bt,
    const float* __restrict__ bias, float* __restrict__ C)
{
    __shared__ ushort A_lds[64 * 40];
    __shared__ ushort B_lds[320 * 40];
    const int tid = threadIdx.x;
    const int w = tid >> 6, l = tid & 63;
    const int c15 = l & 15, khi = (l >> 4) * 8;
    const int m0 = blockIdx.x * 64;
    f32x4 acc[4][5] = {};
    for (int kk = 0; kk < 320; kk += 32) {
        {
            int r = tid >> 2, p = (tid & 3) * 8;
            *(ushort8*)&A_lds[r * 40 + p] = *(const ushort8*)(A + (size_t)(m0 + r) * 320 + kk + p);
        }
        #pragma unroll
        for (int i = 0; i < 5; ++i) {
            int idx = tid + i * 256;
            int n = idx >> 2, p = (idx & 3) * 8;
            *(ushort8*)&B_lds[n * 40 + p] = *(const ushort8*)(Bt + (size_t)n * 320 + kk + p);
        }
        __syncthreads();
        bf16x8 a[4];
        #pragma unroll
        for (int mf = 0; mf < 4; ++mf)
            a[mf] = *(const bf16x8*)&A_lds[(mf * 16 + c15) * 40 + khi];
        #pragma unroll
        for (int f = 0; f < 5; ++f) {
            bf16x8 b = *(const bf16x8*)&B_lds[(w * 80 + f * 16 + c15) * 40 + khi];
            #pragma unroll
            for (int mf = 0; mf < 4; ++mf)
                acc[mf][f] = __builtin_amdgcn_mfma_f32_16x16x32_bf16(a[mf], b, acc[mf][f], 0, 0, 0);
        }
        __syncthreads();
    }
    const int rbase = (l >> 4) * 4;
    #pragma unroll
    for (int mf = 0; mf < 4; ++mf)
        #pragma unroll
        for (int f = 0; f < 5; ++f) {
            int col = w * 80 + f * 16 + c15;
            #pragma unroll
            for (int r = 0; r < 4; ++r)
                C[(size_t)(m0 + mf * 16 + rbase + r) * 320 + col] = acc[mf][f][r] + bias[col];
        }
}

// ---------------------------------------------------------------------------
// k/v projection. grid (10, 2): y=0 -> K (row-major Kb), y=1 -> V (transposed
// into VVt[bt][c][s], s padded to 80). 256 threads, 4 waves x 80 cols.
// ---------------------------------------------------------------------------
__global__ __launch_bounds__(256) void gemm_kv(
    const float* __restrict__ E, const ushort* __restrict__ Wk_t,
    const ushort* __restrict__ Wv_t, ushort* __restrict__ Kb,
    ushort* __restrict__ VVt)
{
    __shared__ ushort A_lds[64 * 40];
    __shared__ ushort B_lds[320 * 40];
    const int tid = threadIdx.x;
    const int w = tid >> 6, l = tid & 63;
    const int c15 = l & 15, khi = (l >> 4) * 8;
    const int mat = blockIdx.y;
    const ushort* Bt = mat ? Wv_t : Wk_t;
    const int m0 = blockIdx.x * 64;
    f32x4 acc[4][5] = {};
    for (int kk = 0; kk < 768; kk += 32) {
        {   // stage A rows (convert, guard M=616)
            int r = tid >> 2, p = (tid & 3) * 8;
            int m = m0 + r;
            ushort* d = &A_lds[r * 40 + p];
            if (m < 616) {
                const float4v* s = (const float4v*)(E + (size_t)m * 768 + kk + p);
                float4v x0 = s[0], x1 = s[1];
                d[0]=f2bf(x0.x); d[1]=f2bf(x0.y); d[2]=f2bf(x0.z); d[3]=f2bf(x0.w);
                d[4]=f2bf(x1.x); d[5]=f2bf(x1.y); d[6]=f2bf(x1.z); d[7]=f2bf(x1.w);
            } else {
                #pragma unroll
                for (int j = 0; j < 8; ++j) d[j] = 0;
            }
        }
        #pragma unroll
        for (int i = 0; i < 5; ++i) {
            int idx = tid + i * 256;
            int n = idx >> 2, p = (idx & 3) * 8;
            *(ushort8*)&B_lds[n * 40 + p] = *(const ushort8*)(Bt + (size_t)n * 768 + kk + p);
        }
        __syncthreads();
        bf16x8 a[4];
        #pragma unroll
        for (int mf = 0; mf < 4; ++mf)
            a[mf] = *(const bf16x8*)&A_lds[(mf * 16 + c15) * 40 + khi];
        #pragma unroll
        for (int f = 0; f < 5; ++f) {
            bf16x8 b = *(const bf16x8*)&B_lds[(w * 80 + f * 16 + c15) * 40 + khi];
            #pragma unroll
            for (int mf = 0; mf < 4; ++mf)
                acc[mf][f] = __builtin_amdgcn_mfma_f32_16x16x32_bf16(a[mf], b, acc[mf][f], 0, 0, 0);
        }
        __syncthreads();
    }
    const int rbase = (l >> 4) * 4;
    #pragma unroll
    for (int mf = 0; mf < 4; ++mf)
        #pragma unroll
        for (int f = 0; f < 5; ++f) {
            int col = w * 80 + f * 16 + c15;
            #pragma unroll
            for (int r = 0; r < 4; ++r) {
                int row = m0 + mf * 16 + rbase + r;
                if (row < 616) {
                    if (mat == 0) {
                        Kb[(size_t)row * 320 + col] = f2bf(acc[mf][f][r]);
                    } else {
                        int bt = row / 77, s = row - bt * 77;
                        VVt[((size_t)bt * 320 + col) * 80 + s] = f2bf(acc[mf][f][r]);
                    }
                }
            }
        }
}

// ---------------------------------------------------------------------------
// v'^T[p][c][m] = sum_e mapper[p][m][e] * V^T[5+p][c][e]   (231 blocks x 320)
// ---------------------------------------------------------------------------
__global__ void vprime_k(const float* __restrict__ mapper, const ushort* __restrict__ VVt,
                         ushort* __restrict__ VPt)
{
    int pm = blockIdx.x;            // p*77 + m
    int p = pm / 77, m = pm - p * 77;
    __shared__ float mp[77];
    int tid = threadIdx.x;          // 320 threads, one per channel c
    if (tid < 77) mp[tid] = mapper[(size_t)pm * 77 + tid];
    __syncthreads();
    const ushort* vrow = VVt + ((size_t)(5 + p) * 320 + tid) * 80;   // contiguous in e
    float acc = 0.f;
    for (int e = 0; e < 77; ++e) acc += mp[e] * bf2f(vrow[e]);
    VPt[((size_t)p * 320 + tid) * 80 + m] = f2bf(acc);
}

// ---------------------------------------------------------------------------
// Fused attention. grid = (T/64, H=8, BT=8). z = OUTPUT batch bt; scores use
// qb = min(bt,4); V from VVt (bt<5) or VPt (bt>=5). 256 thr, 4 waves x 16 rows.
// ---------------------------------------------------------------------------
#define ATT_SCALE 0.15811388300841897f   // 1/sqrt(40)
__global__ __launch_bounds__(256) void attn_k(
    const ushort* __restrict__ Q, const ushort* __restrict__ K,
    const ushort* __restrict__ VVt, const ushort* __restrict__ VPt,
    ushort* __restrict__ O)
{
    __shared__ ushort Q_lds[64 * 72];        // [row][k0..63] (d padded 40->64)
    __shared__ ushort K_lds[80 * 72];        // [s][k0..63]
    __shared__ ushort P_lds[64 * 104];       // [row][s0..95], stride 104
    __shared__ ushort V_lds[48 * 104];       // [dcol0..47][s0..95]
    const int tid = threadIdx.x;
    const int w = tid >> 6, l = tid & 63;
    const int c15 = l & 15, khi = (l >> 4) * 8;
    const int bt = blockIdx.z, h = blockIdx.y, t0 = blockIdx.x * 64;
    const int qb = (bt < 5) ? bt : 4;
    const ushort* Vsrc = (bt < 5) ? (VVt + (size_t)bt * 320 * 80)
                                  : (VPt + (size_t)(bt - 5) * 320 * 80);
    const ushort8 z8 = {0,0,0,0,0,0,0,0};

    for (int i = tid; i < 320; i += 256) {          // Q tile: 64 rows x 5 chunks
        int r = i / 5, c = i - 5 * r;
        *(ushort8*)&Q_lds[r * 72 + c * 8] =
            *(const ushort8*)(Q + (size_t)(qb * 4096 + t0 + r) * 320 + h * 40 + c * 8);
    }
    {   // zero Q kd 40..71 (64 rows x 4 chunks)
        int r = tid >> 2, c = tid & 3;
        *(ushort8*)&Q_lds[r * 72 + 40 + c * 8] = z8;
    }
    for (int i = tid; i < 400; i += 256) {          // K tile: 80 rows x 5 chunks
        int s = i / 5, c = i - 5 * s;
        if (s < 77)
            *(ushort8*)&K_lds[s * 72 + c * 8] =
                *(const ushort8*)(K + (size_t)(qb * 77 + s) * 320 + h * 40 + c * 8);
        else
            *(ushort8*)&K_lds[s * 72 + c * 8] = z8;
    }
    for (int i = tid; i < 320; i += 256) {          // zero K kd 40..71 (80 rows x 4)
        int s = i >> 2, c = i & 3;
        *(ushort8*)&K_lds[s * 72 + 40 + c * 8] = z8;
    }
    for (int i = tid; i < 400; i += 256) {          // V^T tile: 40 rows x 10 chunks
        int dc = i / 10, c = i - 10 * dc;
        *(ushort8*)&V_lds[dc * 104 + c * 8] =
            *(const ushort8*)(Vsrc + ((size_t)h * 40 + dc) * 80 + c * 8);
    }
    for (int i = tid; i < 104; i += 256) {          // zero V dc 40..47 (8 rows x 13)
        int dc = 40 + i / 13, c = i - 13 * (i / 13);
        *(ushort8*)&V_lds[dc * 104 + c * 8] = z8;
    }
    for (int i = tid; i < 192; i += 256) {          // zero P cols 80..103 (64 x 3)
        int r = i / 3, c = i - 3 * r;
        *(ushort8*)&P_lds[r * 104 + 80 + c * 8] = z8;
    }
    __syncthreads();

    // QK^T : rows 16w..16w+15, cols 0..79 (5 frags), K-dim 64 (2 steps)
    f32x4 sacc[5] = {};
    bf16x8 qa[2];
    #pragma unroll
    for (int kt = 0; kt < 2; ++kt)
        qa[kt] = *(const bf16x8*)&Q_lds[(w * 16 + c15) * 72 + kt * 32 + khi];
    #pragma unroll
    for (int f = 0; f < 5; ++f)
        #pragma unroll
        for (int kt = 0; kt < 2; ++kt) {
            bf16x8 kb = *(const bf16x8*)&K_lds[(f * 16 + c15) * 72 + kt * 32 + khi];
            sacc[f] = __builtin_amdgcn_mfma_f32_16x16x32_bf16(qa[kt], kb, sacc[f], 0, 0, 0);
        }

    // masked softmax over s (per C-row; 16-lane shuffle reduce)
    float pv[5][4];
    #pragma unroll
    for (int r = 0; r < 4; ++r) {
        float mx = -1e30f;
        #pragma unroll
        for (int f = 0; f < 5; ++f) {
            float vs = sacc[f][r] * ATT_SCALE;
            bool valid = (f < 4) || (c15 < 13);     // col = 16f + c15 < 77
            pv[f][r] = valid ? vs : -1e30f;
            mx = fmaxf(mx, pv[f][r]);
        }
        #pragma unroll
        for (int d = 1; d < 16; d <<= 1) mx = fmaxf(mx, __shfl_xor(mx, d));
        float sum = 0.f;
        #pragma unroll
        for (int f = 0; f < 5; ++f) {
            float e = (pv[f][r] > -1e29f) ? __expf(pv[f][r] - mx) : 0.f;
            pv[f][r] = e; sum += e;
        }
        #pragma unroll
        for (int d = 1; d < 16; d <<= 1) sum += __shfl_xor(sum, d);
        float inv = 1.f / sum;
        #pragma unroll
        for (int f = 0; f < 5; ++f) pv[f][r] *= inv;
    }
    const int rbase = (l >> 4) * 4;
    #pragma unroll
    for (int r = 0; r < 4; ++r)
        #pragma unroll
        for (int f = 0; f < 5; ++f)
            P_lds[(w * 16 + rbase + r) * 104 + f * 16 + c15] = f2bf(pv[f][r]);
    __syncthreads();

    // PV: out rows 16w.., dcols 0..47 (3 frags), K-dim 96 (3 steps)
    bf16x8 pa[3];
    #pragma unroll
    for (int kt = 0; kt < 3; ++kt)
        pa[kt] = *(const bf16x8*)&P_lds[(w * 16 + c15) * 104 + kt * 32 + khi];
    f32x4 oacc[3] = {};
    #pragma unroll
    for (int f = 0; f < 3; ++f)
        #pragma unroll
        for (int kt = 0; kt < 3; ++kt) {
            bf16x8 vb = *(const bf16x8*)&V_lds[(f * 16 + c15) * 104 + kt * 32 + khi];
            oacc[f] = __builtin_amdgcn_mfma_f32_16x16x32_bf16(pa[kt], vb, oacc[f], 0, 0, 0);
        }
    #pragma unroll
    for (int f = 0; f < 3; ++f) {
        int col = f * 16 + c15;
        if (col < 40) {
            #pragma unroll
            for (int r = 0; r < 4; ++r)
                O[(size_t)(bt * 4096 + t0 + w * 16 + rbase + r) * 320 + h * 40 + col]
                    = f2bf(oacc[f][r]);
        }
    }
}

// ---------------------------------------------------------------------------
extern "C" void kernel_launch(void* const* d_in, const int* in_sizes, int n_in,
                              void* d_out, int out_size, void* d_ws, size_t ws_size,
                              hipStream_t stream) {
    (void)in_sizes; (void)n_in; (void)out_size; (void)ws_size;
    const float* hs     = (const float*)d_in[0];   // (8,4096,320)
    const float* ehs    = (const float*)d_in[1];   // (8,77,768)
    const float* mapper = (const float*)d_in[2];   // (3,77,77)
    const float* Wq     = (const float*)d_in[3];   // (320,320)
    const float* Wk     = (const float*)d_in[4];   // (768,320)
    const float* Wv     = (const float*)d_in[5];   // (768,320)
    const float* Wo     = (const float*)d_in[6];   // (320,320)
    const float* bo     = (const float*)d_in[7];   // (320,)
    float* out = (float*)d_out;

    ushort* ws   = (ushort*)d_ws;                  // ~36.4 MB of bf16 scratch
    ushort* Wq_t = ws;                             // 320*320
    ushort* Wk_t = Wq_t + 320 * 320;               // 320*768
    ushort* Wv_t = Wk_t + 320 * 768;
    ushort* Wo_t = Wv_t + 320 * 768;               // 320*320
    ushort* Qb   = Wo_t + 320 * 320;               // 20480*320
    ushort* Kb   = Qb + 20480 * 320;               // 616*320
    ushort* VVt  = Kb + 616 * 320;                 // 8*320*80  (V^T, s padded to 80)
    ushort* VPt  = VVt + 8 * 320 * 80;             // 3*320*80  (V'^T)
    ushort* AO   = VPt + 3 * 320 * 80;             // 32768*320

    transpose_all<<<680, 256, 0, stream>>>(Wq, Wk, Wv, Wo, Wq_t, Wk_t, Wv_t, Wo_t);
    gemm_kv<<<dim3(10, 2), 256, 0, stream>>>(ehs, Wk_t, Wv_t, Kb, VVt);
    gemm_qproj<<<320, 256, 0, stream>>>(hs, Wq_t, Qb);
    vprime_k<<<231, 320, 0, stream>>>(mapper, VVt, VPt);
    attn_k<<<dim3(64, 8, 8), 256, 0, stream>>>(Qb, Kb, VVt, VPt, AO);
    gemm_out<<<512, 256, 0, stream>>>(AO, Wo_t, bo, out);
}

// Round 5
// 81.952 us; speedup vs baseline: 2.4660x; 1.4166x over previous
//
#include <hip/hip_runtime.h>
#include <hip/hip_bf16.h>

typedef unsigned short ushort;
typedef __attribute__((ext_vector_type(8))) short bf16x8;     // MFMA A/B frag (8 bf16)
typedef __attribute__((ext_vector_type(8))) unsigned short ushort8;
typedef __attribute__((ext_vector_type(4))) float f32x4;      // MFMA C/D frag
typedef __attribute__((ext_vector_type(4))) float float4v;

__device__ __forceinline__ ushort f2bf(float f) {
    union { float f; unsigned u; } v; v.f = f;
    unsigned r = v.u + 0x7FFFu + ((v.u >> 16) & 1u);
    return (ushort)(r >> 16);
}
__device__ __forceinline__ float bf2f(ushort u) {
    union { unsigned u; float f; } v; v.u = ((unsigned)u) << 16;
    return v.f;
}

// ---------------------------------------------------------------------------
// Merged LDS-tiled transpose + fp32->bf16 for all four weights.
// dst[n*K + k] = bf16(src[k*320 + n]);  N = 320 for all, K in {320,768}.
// ---------------------------------------------------------------------------
__global__ __launch_bounds__(256) void transpose_all(
    const float* __restrict__ Wq, const float* __restrict__ Wk,
    const float* __restrict__ Wv, const float* __restrict__ Wo,
    ushort* __restrict__ Wq_t, ushort* __restrict__ Wk_t,
    ushort* __restrict__ Wv_t, ushort* __restrict__ Wo_t)
{
    __shared__ ushort t[32][33];
    int b = blockIdx.x;
    const float* src; ushort* dst; int K; int tb;
    if (b < 100)      { src = Wq; dst = Wq_t; K = 320; tb = b; }
    else if (b < 340) { src = Wk; dst = Wk_t; K = 768; tb = b - 100; }
    else if (b < 580) { src = Wv; dst = Wv_t; K = 768; tb = b - 340; }
    else              { src = Wo; dst = Wo_t; K = 320; tb = b - 580; }
    int tc = tb % 10, tr = tb / 10;               // tile col (n), tile row (k)
    int tx = threadIdx.x & 31, ty = threadIdx.x >> 5;
    #pragma unroll
    for (int p = 0; p < 4; ++p) {
        int k = tr * 32 + ty + p * 8, n = tc * 32 + tx;
        t[ty + p * 8][tx] = f2bf(src[(size_t)k * 320 + n]);
    }
    __syncthreads();
    #pragma unroll
    for (int p = 0; p < 4; ++p) {
        int n = tc * 32 + ty + p * 8, k = tr * 32 + tx;
        dst[(size_t)n * K + k] = t[tx][ty + p * 8];
    }
}

// ---------------------------------------------------------------------------
// Fused q-projection + split-K k/v-projection partials.
// bid < 160 : kv partial. mtile=bid%10, mat=(bid/10)&1, ks=bid/20 (8 splits of 96).
//             part[(mat*8+ks)][row 0..639][col 0..319] f32.
// bid >= 160: qproj tile m0=(bid-160)*64, K=320, Qb bf16 out.
// Both: 256 thr, 4 waves x 80 cols, double-buffered LDS, 1 barrier/iter.
// ---------------------------------------------------------------------------
__global__ __launch_bounds__(256) void gemm_qkv(
    const float* __restrict__ A, const ushort* __restrict__ Wq_t,
    const float* __restrict__ E, const ushort* __restrict__ Wk_t,
    const ushort* __restrict__ Wv_t,
    ushort* __restrict__ Qb, float* __restrict__ part)
{
    __shared__ ushort A_lds[2][64 * 40];
    __shared__ ushort B_lds[2][320 * 40];
    const int tid = threadIdx.x;
    const int w = tid >> 6, l = tid & 63;
    const int c15 = l & 15, khi = (l >> 4) * 8;
    const int r = tid >> 2, p = (tid & 3) * 8;
    const int rbase = (l >> 4) * 4;
    f32x4 acc[4][5] = {};
    const int bid = blockIdx.x;

    if (bid < 160) {
        const int mtile = bid % 10, mat = (bid / 10) & 1, ks = bid / 20;
        const int m0 = mtile * 64, kk0 = ks * 96;
        const ushort* Bt = mat ? Wv_t : Wk_t;
        const int m = m0 + r;
        const bool live = (m < 616);
        const float* Abase = E + (size_t)(live ? m : 0) * 768 + p;
        float4v a0 = {0,0,0,0}, a1 = {0,0,0,0};
        ushort8 breg[5];
        if (live) { a0 = *(const float4v*)(Abase + kk0); a1 = *(const float4v*)(Abase + kk0 + 4); }
        #pragma unroll
        for (int i = 0; i < 5; ++i) {
            int idx = tid + i * 256; int n = idx >> 2, q = (idx & 3) * 8;
            breg[i] = *(const ushort8*)(Bt + (size_t)n * 768 + kk0 + q);
        }
        {
            ushort* d = &A_lds[0][r * 40 + p];
            d[0]=f2bf(a0.x); d[1]=f2bf(a0.y); d[2]=f2bf(a0.z); d[3]=f2bf(a0.w);
            d[4]=f2bf(a1.x); d[5]=f2bf(a1.y); d[6]=f2bf(a1.z); d[7]=f2bf(a1.w);
            #pragma unroll
            for (int i = 0; i < 5; ++i) {
                int idx = tid + i * 256; int n = idx >> 2, q = (idx & 3) * 8;
                *(ushort8*)&B_lds[0][n * 40 + q] = breg[i];
            }
        }
        __syncthreads();
        for (int k = 0; k < 3; ++k) {
            const int cur = k & 1;
            if (k < 2) {
                int kk = kk0 + (k + 1) * 32;
                if (live) { a0 = *(const float4v*)(Abase + kk); a1 = *(const float4v*)(Abase + kk + 4); }
                #pragma unroll
                for (int i = 0; i < 5; ++i) {
                    int idx = tid + i * 256; int n = idx >> 2, q = (idx & 3) * 8;
                    breg[i] = *(const ushort8*)(Bt + (size_t)n * 768 + kk + q);
                }
            }
            bf16x8 a[4];
            #pragma unroll
            for (int mf = 0; mf < 4; ++mf)
                a[mf] = *(const bf16x8*)&A_lds[cur][(mf * 16 + c15) * 40 + khi];
            #pragma unroll
            for (int f = 0; f < 5; ++f) {
                bf16x8 b = *(const bf16x8*)&B_lds[cur][(w * 80 + f * 16 + c15) * 40 + khi];
                #pragma unroll
                for (int mf = 0; mf < 4; ++mf)
                    acc[mf][f] = __builtin_amdgcn_mfma_f32_16x16x32_bf16(a[mf], b, acc[mf][f], 0, 0, 0);
            }
            if (k < 2) {
                const int nxt = cur ^ 1;
                ushort* d = &A_lds[nxt][r * 40 + p];
                d[0]=f2bf(a0.x); d[1]=f2bf(a0.y); d[2]=f2bf(a0.z); d[3]=f2bf(a0.w);
                d[4]=f2bf(a1.x); d[5]=f2bf(a1.y); d[6]=f2bf(a1.z); d[7]=f2bf(a1.w);
                #pragma unroll
                for (int i = 0; i < 5; ++i) {
                    int idx = tid + i * 256; int n = idx >> 2, q = (idx & 3) * 8;
                    *(ushort8*)&B_lds[nxt][n * 40 + q] = breg[i];
                }
                __syncthreads();
            }
        }
        float* dst = part + (size_t)(mat * 8 + ks) * 640 * 320;
        #pragma unroll
        for (int mf = 0; mf < 4; ++mf)
            #pragma unroll
            for (int f = 0; f < 5; ++f) {
                int col = w * 80 + f * 16 + c15;
                #pragma unroll
                for (int rr = 0; rr < 4; ++rr)
                    dst[(size_t)(m0 + mf * 16 + rbase + rr) * 320 + col] = acc[mf][f][rr];
            }
    } else {
        const int m0 = (bid - 160) * 64;
        const float* Abase = A + (size_t)(m0 + r) * 320 + p;
        float4v a0, a1; ushort8 breg[5];
        a0 = *(const float4v*)(Abase + 0);
        a1 = *(const float4v*)(Abase + 4);
        #pragma unroll
        for (int i = 0; i < 5; ++i) {
            int idx = tid + i * 256; int n = idx >> 2, q = (idx & 3) * 8;
            breg[i] = *(const ushort8*)(Wq_t + (size_t)n * 320 + q);
        }
        {
            ushort* d = &A_lds[0][r * 40 + p];
            d[0]=f2bf(a0.x); d[1]=f2bf(a0.y); d[2]=f2bf(a0.z); d[3]=f2bf(a0.w);
            d[4]=f2bf(a1.x); d[5]=f2bf(a1.y); d[6]=f2bf(a1.z); d[7]=f2bf(a1.w);
            #pragma unroll
            for (int i = 0; i < 5; ++i) {
                int idx = tid + i * 256; int n = idx >> 2, q = (idx & 3) * 8;
                *(ushort8*)&B_lds[0][n * 40 + q] = breg[i];
            }
        }
        __syncthreads();
        for (int k = 0; k < 10; ++k) {
            const int cur = k & 1;
            if (k < 9) {
                int kk = (k + 1) * 32;
                a0 = *(const float4v*)(Abase + kk);
                a1 = *(const float4v*)(Abase + kk + 4);
                #pragma unroll
                for (int i = 0; i < 5; ++i) {
                    int idx = tid + i * 256; int n = idx >> 2, q = (idx & 3) * 8;
                    breg[i] = *(const ushort8*)(Wq_t + (size_t)n * 320 + kk + q);
                }
            }
            bf16x8 a[4];
            #pragma unroll
            for (int mf = 0; mf < 4; ++mf)
                a[mf] = *(const bf16x8*)&A_lds[cur][(mf * 16 + c15) * 40 + khi];
            #pragma unroll
            for (int f = 0; f < 5; ++f) {
                bf16x8 b = *(const bf16x8*)&B_lds[cur][(w * 80 + f * 16 + c15) * 40 + khi];
                #pragma unroll
                for (int mf = 0; mf < 4; ++mf)
                    acc[mf][f] = __builtin_amdgcn_mfma_f32_16x16x32_bf16(a[mf], b, acc[mf][f], 0, 0, 0);
            }
            if (k < 9) {
                const int nxt = cur ^ 1;
                ushort* d = &A_lds[nxt][r * 40 + p];
                d[0]=f2bf(a0.x); d[1]=f2bf(a0.y); d[2]=f2bf(a0.z); d[3]=f2bf(a0.w);
                d[4]=f2bf(a1.x); d[5]=f2bf(a1.y); d[6]=f2bf(a1.z); d[7]=f2bf(a1.w);
                #pragma unroll
                for (int i = 0; i < 5; ++i) {
                    int idx = tid + i * 256; int n = idx >> 2, q = (idx & 3) * 8;
                    *(ushort8*)&B_lds[nxt][n * 40 + q] = breg[i];
                }
                __syncthreads();
            }
        }
        #pragma unroll
        for (int mf = 0; mf < 4; ++mf)
            #pragma unroll
            for (int f = 0; f < 5; ++f) {
                int col = w * 80 + f * 16 + c15;
                #pragma unroll
                for (int rr = 0; rr < 4; ++rr)
                    Qb[(size_t)(m0 + mf * 16 + rbase + rr) * 320 + col] = f2bf(acc[mf][f][rr]);
            }
    }
}

// ---------------------------------------------------------------------------
// Reduce 8 split-K partials -> Kb (row-major) / VVt (transposed, s padded 80).
// grid (770, 2), 256 thr.
// ---------------------------------------------------------------------------
__global__ __launch_bounds__(256) void kv_reduce(
    const float* __restrict__ part, ushort* __restrict__ Kb, ushort* __restrict__ VVt)
{
    int idx = blockIdx.x * 256 + threadIdx.x;
    if (idx >= 616 * 320) return;
    int mat = blockIdx.y;
    int row = idx / 320, col = idx - row * 320;
    float s = 0.f;
    #pragma unroll
    for (int ks = 0; ks < 8; ++ks)
        s += part[((size_t)(mat * 8 + ks) * 640 + row) * 320 + col];
    ushort b = f2bf(s);
    if (mat == 0) {
        Kb[(size_t)row * 320 + col] = b;
    } else {
        int bt = row / 77, ss = row - bt * 77;
        VVt[((size_t)bt * 320 + col) * 80 + ss] = b;
    }
}

// ---------------------------------------------------------------------------
// v'^T[p][c][m] = sum_e mapper[p][m][e] * V^T[5+p][c][e]   (231 blocks x 320)
// ---------------------------------------------------------------------------
__global__ void vprime_k(const float* __restrict__ mapper, const ushort* __restrict__ VVt,
                         ushort* __restrict__ VPt)
{
    int pm = blockIdx.x;            // p*77 + m
    int p = pm / 77, m = pm - p * 77;
    __shared__ float mp[77];
    int tid = threadIdx.x;          // 320 threads, one per channel c
    if (tid < 77) mp[tid] = mapper[(size_t)pm * 77 + tid];
    __syncthreads();
    const ushort* vrow = VVt + ((size_t)(5 + p) * 320 + tid) * 80;   // contiguous in e
    float acc = 0.f;
    for (int e = 0; e < 77; ++e) acc += mp[e] * bf2f(vrow[e]);
    VPt[((size_t)p * 320 + tid) * 80 + m] = f2bf(acc);
}

// ---------------------------------------------------------------------------
// Fused attention. grid = (T/64, H=8, BT=8). z = OUTPUT batch bt; scores use
// qb = min(bt,4); V from VVt (bt<5) or VPt (bt>=5). 256 thr, 4 waves x 16 rows.
// ---------------------------------------------------------------------------
#define ATT_SCALE 0.15811388300841897f   // 1/sqrt(40)
__global__ __launch_bounds__(256) void attn_k(
    const ushort* __restrict__ Q, const ushort* __restrict__ K,
    const ushort* __restrict__ VVt, const ushort* __restrict__ VPt,
    ushort* __restrict__ O)
{
    __shared__ ushort Q_lds[64 * 72];        // [row][k0..63] (d padded 40->64)
    __shared__ ushort K_lds[80 * 72];        // [s][k0..63]
    __shared__ ushort P_lds[64 * 104];       // [row][s0..95], stride 104
    __shared__ ushort V_lds[48 * 104];       // [dcol0..47][s0..95]
    const int tid = threadIdx.x;
    const int w = tid >> 6, l = tid & 63;
    const int c15 = l & 15, khi = (l >> 4) * 8;
    const int bt = blockIdx.z, h = blockIdx.y, t0 = blockIdx.x * 64;
    const int qb = (bt < 5) ? bt : 4;
    const ushort* Vsrc = (bt < 5) ? (VVt + (size_t)bt * 320 * 80)
                                  : (VPt + (size_t)(bt - 5) * 320 * 80);
    const ushort8 z8 = {0,0,0,0,0,0,0,0};

    for (int i = tid; i < 320; i += 256) {          // Q tile: 64 rows x 5 chunks
        int r = i / 5, c = i - 5 * r;
        *(ushort8*)&Q_lds[r * 72 + c * 8] =
            *(const ushort8*)(Q + (size_t)(qb * 4096 + t0 + r) * 320 + h * 40 + c * 8);
    }
    {   // zero Q kd 40..71 (64 rows x 4 chunks)
        int r = tid >> 2, c = tid & 3;
        *(ushort8*)&Q_lds[r * 72 + 40 + c * 8] = z8;
    }
    for (int i = tid; i < 400; i += 256) {          // K tile: 80 rows x 5 chunks
        int s = i / 5, c = i - 5 * s;
        if (s < 77)
            *(ushort8*)&K_lds[s * 72 + c * 8] =
                *(const ushort8*)(K + (size_t)(qb * 77 + s) * 320 + h * 40 + c * 8);
        else
            *(ushort8*)&K_lds[s * 72 + c * 8] = z8;
    }
    for (int i = tid; i < 320; i += 256) {          // zero K kd 40..71 (80 rows x 4)
        int s = i >> 2, c = i & 3;
        *(ushort8*)&K_lds[s * 72 + 40 + c * 8] = z8;
    }
    for (int i = tid; i < 400; i += 256) {          // V^T tile: 40 rows x 10 chunks
        int dc = i / 10, c = i - 10 * dc;
        *(ushort8*)&V_lds[dc * 104 + c * 8] =
            *(const ushort8*)(Vsrc + ((size_t)h * 40 + dc) * 80 + c * 8);
    }
    for (int i = tid; i < 104; i += 256) {          // zero V dc 40..47 (8 rows x 13)
        int dc = 40 + i / 13, c = i - 13 * (i / 13);
        *(ushort8*)&V_lds[dc * 104 + c * 8] = z8;
    }
    for (int i = tid; i < 192; i += 256) {          // zero P cols 80..103 (64 x 3)
        int r = i / 3, c = i - 3 * r;
        *(ushort8*)&P_lds[r * 104 + 80 + c * 8] = z8;
    }
    __syncthreads();

    // QK^T : rows 16w..16w+15, cols 0..79 (5 frags), K-dim 64 (2 steps)
    f32x4 sacc[5] = {};
    bf16x8 qa[2];
    #pragma unroll
    for (int kt = 0; kt < 2; ++kt)
        qa[kt] = *(const bf16x8*)&Q_lds[(w * 16 + c15) * 72 + kt * 32 + khi];
    #pragma unroll
    for (int f = 0; f < 5; ++f)
        #pragma unroll
        for (int kt = 0; kt < 2; ++kt) {
            bf16x8 kb = *(const bf16x8*)&K_lds[(f * 16 + c15) * 72 + kt * 32 + khi];
            sacc[f] = __builtin_amdgcn_mfma_f32_16x16x32_bf16(qa[kt], kb, sacc[f], 0, 0, 0);
        }

    // masked softmax over s (per C-row; 16-lane shuffle reduce)
    float pv[5][4];
    #pragma unroll
    for (int r = 0; r < 4; ++r) {
        float mx = -1e30f;
        #pragma unroll
        for (int f = 0; f < 5; ++f) {
            float vs = sacc[f][r] * ATT_SCALE;
            bool valid = (f < 4) || (c15 < 13);     // col = 16f + c15 < 77
            pv[f][r] = valid ? vs : -1e30f;
            mx = fmaxf(mx, pv[f][r]);
        }
        #pragma unroll
        for (int d = 1; d < 16; d <<= 1) mx = fmaxf(mx, __shfl_xor(mx, d));
        float sum = 0.f;
        #pragma unroll
        for (int f = 0; f < 5; ++f) {
            float e = (pv[f][r] > -1e29f) ? __expf(pv[f][r] - mx) : 0.f;
            pv[f][r] = e; sum += e;
        }
        #pragma unroll
        for (int d = 1; d < 16; d <<= 1) sum += __shfl_xor(sum, d);
        float inv = 1.f / sum;
        #pragma unroll
        for (int f = 0; f < 5; ++f) pv[f][r] *= inv;
    }
    const int rbase = (l >> 4) * 4;
    #pragma unroll
    for (int r = 0; r < 4; ++r)
        #pragma unroll
        for (int f = 0; f < 5; ++f)
            P_lds[(w * 16 + rbase + r) * 104 + f * 16 + c15] = f2bf(pv[f][r]);
    __syncthreads();

    // PV: out rows 16w.., dcols 0..47 (3 frags), K-dim 96 (3 steps)
    bf16x8 pa[3];
    #pragma unroll
    for (int kt = 0; kt < 3; ++kt)
        pa[kt] = *(const bf16x8*)&P_lds[(w * 16 + c15) * 104 + kt * 32 + khi];
    f32x4 oacc[3] = {};
    #pragma unroll
    for (int f = 0; f < 3; ++f)
        #pragma unroll
        for (int kt = 0; kt < 3; ++kt) {
            bf16x8 vb = *(const bf16x8*)&V_lds[(f * 16 + c15) * 104 + kt * 32 + khi];
            oacc[f] = __builtin_amdgcn_mfma_f32_16x16x32_bf16(pa[kt], vb, oacc[f], 0, 0, 0);
        }
    #pragma unroll
    for (int f = 0; f < 3; ++f) {
        int col = f * 16 + c15;
        if (col < 40) {
            #pragma unroll
            for (int r = 0; r < 4; ++r)
                O[(size_t)(bt * 4096 + t0 + w * 16 + rbase + r) * 320 + h * 40 + col]
                    = f2bf(oacc[f][r]);
        }
    }
}

// ---------------------------------------------------------------------------
// out-projection: out_f32[m, n] = A_bf16[m, 0:320] @ Wo_t^T + bo[n]
// Double-buffered LDS, 1 barrier/iter.
// ---------------------------------------------------------------------------
__global__ __launch_bounds__(256) void gemm_out(
    const ushort* __restrict__ A, const ushort* __restrict__ Bt,
    const float* __restrict__ bias, float* __restrict__ C)
{
    __shared__ ushort A_lds[2][64 * 40];
    __shared__ ushort B_lds[2][320 * 40];
    const int tid = threadIdx.x;
    const int w = tid >> 6, l = tid & 63;
    const int c15 = l & 15, khi = (l >> 4) * 8;
    const int r = tid >> 2, p = (tid & 3) * 8;
    const int m0 = blockIdx.x * 64;
    f32x4 acc[4][5] = {};
    const ushort* Abase = A + (size_t)(m0 + r) * 320 + p;
    ushort8 areg; ushort8 breg[5];
    areg = *(const ushort8*)(Abase + 0);
    #pragma unroll
    for (int i = 0; i < 5; ++i) {
        int idx = tid + i * 256; int n = idx >> 2, q = (idx & 3) * 8;
        breg[i] = *(const ushort8*)(Bt + (size_t)n * 320 + q);
    }
    {
        *(ushort8*)&A_lds[0][r * 40 + p] = areg;
        #pragma unroll
        for (int i = 0; i < 5; ++i) {
            int idx = tid + i * 256; int n = idx >> 2, q = (idx & 3) * 8;
            *(ushort8*)&B_lds[0][n * 40 + q] = breg[i];
        }
    }
    __syncthreads();
    for (int k = 0; k < 10; ++k) {
        const int cur = k & 1;
        if (k < 9) {
            int kk = (k + 1) * 32;
            areg = *(const ushort8*)(Abase + kk);
            #pragma unroll
            for (int i = 0; i < 5; ++i) {
                int idx = tid + i * 256; int n = idx >> 2, q = (idx & 3) * 8;
                breg[i] = *(const ushort8*)(Bt + (size_t)n * 320 + kk + q);
            }
        }
        bf16x8 a[4];
        #pragma unroll
        for (int mf = 0; mf < 4; ++mf)
            a[mf] = *(const bf16x8*)&A_lds[cur][(mf * 16 + c15) * 40 + khi];
        #pragma unroll
        for (int f = 0; f < 5; ++f) {
            bf16x8 b = *(const bf16x8*)&B_lds[cur][(w * 80 + f * 16 + c15) * 40 + khi];
            #pragma unroll
            for (int mf = 0; mf < 4; ++mf)
                acc[mf][f] = __builtin_amdgcn_mfma_f32_16x16x32_bf16(a[mf], b, acc[mf][f], 0, 0, 0);
        }
        if (k < 9) {
            const int nxt = cur ^ 1;
            *(ushort8*)&A_lds[nxt][r * 40 + p] = areg;
            #pragma unroll
            for (int i = 0; i < 5; ++i) {
                int idx = tid + i * 256; int n = idx >> 2, q = (idx & 3) * 8;
                *(ushort8*)&B_lds[nxt][n * 40 + q] = breg[i];
            }
            __syncthreads();
        }
    }
    const int rbase = (l >> 4) * 4;
    #pragma unroll
    for (int mf = 0; mf < 4; ++mf)
        #pragma unroll
        for (int f = 0; f < 5; ++f) {
            int col = w * 80 + f * 16 + c15;
            #pragma unroll
            for (int rr = 0; rr < 4; ++rr)
                C[(size_t)(m0 + mf * 16 + rbase + rr) * 320 + col] = acc[mf][f][rr] + bias[col];
        }
}

// ---------------------------------------------------------------------------
extern "C" void kernel_launch(void* const* d_in, const int* in_sizes, int n_in,
                              void* d_out, int out_size, void* d_ws, size_t ws_size,
                              hipStream_t stream) {
    (void)in_sizes; (void)n_in; (void)out_size; (void)ws_size;
    const float* hs     = (const float*)d_in[0];   // (8,4096,320)
    const float* ehs    = (const float*)d_in[1];   // (8,77,768)
    const float* mapper = (const float*)d_in[2];   // (3,77,77)
    const float* Wq     = (const float*)d_in[3];   // (320,320)
    const float* Wk     = (const float*)d_in[4];   // (768,320)
    const float* Wv     = (const float*)d_in[5];   // (768,320)
    const float* Wo     = (const float*)d_in[6];   // (320,320)
    const float* bo     = (const float*)d_in[7];   // (320,)
    float* out = (float*)d_out;

    ushort* ws   = (ushort*)d_ws;
    ushort* Wq_t = ws;                             // 320*320
    ushort* Wk_t = Wq_t + 320 * 320;               // 320*768
    ushort* Wv_t = Wk_t + 320 * 768;
    ushort* Wo_t = Wv_t + 320 * 768;               // 320*320
    ushort* Qb   = Wo_t + 320 * 320;               // 20480*320
    ushort* Kb   = Qb + 20480 * 320;               // 616*320
    ushort* VVt  = Kb + 616 * 320;                 // 8*320*80  (V^T, s padded to 80)
    ushort* VPt  = VVt + 8 * 320 * 80;             // 3*320*80  (V'^T)
    ushort* AO   = VPt + 3 * 320 * 80;             // 32768*320
    float*  part = (float*)AO;                     // 16*640*320 f32 = 13.1 MB,
                                                   // aliases AO (consumed pre-attn)

    transpose_all<<<680, 256, 0, stream>>>(Wq, Wk, Wv, Wo, Wq_t, Wk_t, Wv_t, Wo_t);
    gemm_qkv<<<480, 256, 0, stream>>>(hs, Wq_t, ehs, Wk_t, Wv_t, Qb, part);
    kv_reduce<<<dim3(770, 2), 256, 0, stream>>>(part, Kb, VVt);
    vprime_k<<<231, 320, 0, stream>>>(mapper, VVt, VPt);
    attn_k<<<dim3(64, 8, 8), 256, 0, stream>>>(Qb, Kb, VVt, VPt, AO);
    gemm_out<<<512, 256, 0, stream>>>(AO, Wo_t, bo, out);
}